// Round 1
// baseline (135.711 us; speedup 1.0000x reference)
//
#include <hip/hip_runtime.h>
#include <math.h>

// FM layer: logits = bias + segsum(lw[ids]) + 0.5*sum_d(summed_d^2 - segsum(x_d^2))
// outputs: [logits (B), logits_adjusted (B), probabilities (B)], B=out_size/3.
// segment_ids sorted -> each segment is a contiguous [start,end) range of nnz.
// One wave (64 lanes) per segment; quad-of-lanes per nnz element with float4
// embedding-row loads (64B per element, one cache line).

__global__ __launch_bounds__(256) void fm_fused_kernel(
    const int* __restrict__ ids,
    const int* __restrict__ segs,
    const float* __restrict__ bias,
    const float* __restrict__ lw,
    const float* __restrict__ cw,
    float* __restrict__ out,
    int nnz, int batch)
{
    const int wave = threadIdx.x >> 6;      // wave index in block: 0..3
    const int wl   = threadIdx.x & 63;      // lane in wave
    const int b    = blockIdx.x * 4 + wave; // segment this wave owns
    if (b >= batch) return;

    // --- segment bounds via binary search (lower_bound).
    // lanes 0-31 search for b, lanes 32-63 for b+1 (uniform within each half).
    int target = b + (wl >> 5);
    int lo = 0, hi = nnz;
    while (lo < hi) {
        int mid = (lo + hi) >> 1;
        if (segs[mid] < target) lo = mid + 1; else hi = mid;
    }
    const int start = __shfl(lo, 0);
    const int end   = __shfl(lo, 32);

    // --- gather: 16 elements per iteration; quad of lanes per element.
    // lane = e*4 + c: element slot e (0..15), float4 slot c (components 4c..4c+3).
    const int e = wl >> 2;
    const int c = wl & 3;

    float4 sd = make_float4(0.f, 0.f, 0.f, 0.f); // per-component running sum
    float ssq  = 0.f;  // sum over elements & owned components of x^2
    float slin = 0.f;  // linear_w partial (only c==0 lanes)

    for (int i = start + e; i < end; i += 16) {
        const int id = ids[i];
        const float4 x = *reinterpret_cast<const float4*>(cw + ((size_t)id << 4) + (c << 2));
        sd.x += x.x; sd.y += x.y; sd.z += x.z; sd.w += x.w;
        ssq = fmaf(x.x, x.x, ssq);
        ssq = fmaf(x.y, x.y, ssq);
        ssq = fmaf(x.z, x.z, ssq);
        ssq = fmaf(x.w, x.w, ssq);
        if (c == 0) slin += lw[id];
    }

    // --- reduce across the 16 element-slots (lanes sharing the same c).
    #pragma unroll
    for (int m = 4; m <= 32; m <<= 1) {
        sd.x += __shfl_xor(sd.x, m);
        sd.y += __shfl_xor(sd.y, m);
        sd.z += __shfl_xor(sd.z, m);
        sd.w += __shfl_xor(sd.w, m);
        ssq  += __shfl_xor(ssq,  m);
        slin += __shfl_xor(slin, m);
    }
    // each lane now holds summed[] complete for its 4 components.
    float q = sd.x*sd.x + sd.y*sd.y + sd.z*sd.z + sd.w*sd.w;
    // finish across the 4 component-groups (c = 0..3).
    #pragma unroll
    for (int m = 1; m <= 2; m <<= 1) {
        q    += __shfl_xor(q,    m);
        ssq  += __shfl_xor(ssq,  m);
        slin += __shfl_xor(slin, m);
    }

    if (wl == 0) {
        const float logit = bias[0] + slin + 0.5f * (q - ssq);
        const float adj   = logit;  // + logf(NEG_SAMPLING_RATE=1.0f) == 0
        out[b]             = logit;
        out[batch + b]     = adj;
        out[2 * batch + b] = 1.0f / (1.0f + expf(-adj));
    }
}

extern "C" void kernel_launch(void* const* d_in, const int* in_sizes, int n_in,
                              void* d_out, int out_size, void* d_ws, size_t ws_size,
                              hipStream_t stream) {
    const int*   ids  = (const int*)d_in[0];
    const int*   segs = (const int*)d_in[1];
    // d_in[2] = batch_size scalar (int32) — batch derived from out_size instead.
    const float* bias = (const float*)d_in[3];
    const float* lw   = (const float*)d_in[4];
    const float* cw   = (const float*)d_in[5];
    float*       out  = (float*)d_out;

    const int nnz   = in_sizes[0];
    const int batch = out_size / 3;

    const int waves_per_block = 4;
    const int grid = (batch + waves_per_block - 1) / waves_per_block;
    fm_fused_kernel<<<grid, 256, 0, stream>>>(ids, segs, bias, lw, cw, out, nnz, batch);
}

// Round 3
// 125.027 us; speedup vs baseline: 1.0855x; 1.0855x over previous
//
#include <hip/hip_runtime.h>
#include <math.h>

// FM layer: logits = bias + segsum(lw[ids]) + 0.5*sum_d((segsum x_d)^2 - segsum(x_d^2))
// outputs: [logits (B), logits_adjusted (B), probabilities (B)], B = out_size/3.
//
// Two kernels:
//  1) seg_starts_kernel: one streaming pass over sorted segs -> starts[b] in d_ws
//     (kills the per-wave 20-deep dependent-load binary search of R0).
//  2) fm_fused_kernel: one wave per segment; one LANE per nnz element, each lane
//     loads the full 64B embedding row (4x float4) -> ~64 cache lines in flight
//     per wave, max MLP for the random gather.

__global__ __launch_bounds__(256) void seg_starts_kernel(
    const int* __restrict__ segs, int* __restrict__ starts, int nnz, int batch)
{
    const int i = blockIdx.x * blockDim.x + threadIdx.x;
    if (i >= nnz) return;
    const int cur = segs[i];
    if (i == 0) {
        for (int b = 0; b <= cur; ++b) starts[b] = 0;
    } else {
        const int prev = segs[i - 1];
        for (int b = prev + 1; b <= cur; ++b) starts[b] = i;
    }
    if (i == nnz - 1) {
        for (int b = cur + 1; b <= batch; ++b) starts[b] = nnz;
    }
}

__global__ __launch_bounds__(256) void fm_fused_kernel(
    const int* __restrict__ ids,
    const int* __restrict__ starts,
    const float* __restrict__ bias,
    const float* __restrict__ lw,
    const float* __restrict__ cw,
    float* __restrict__ out,
    int batch)
{
    const int wave = threadIdx.x >> 6;      // wave in block: 0..3
    const int wl   = threadIdx.x & 63;      // lane in wave
    const int b    = blockIdx.x * 4 + wave; // segment this wave owns
    if (b >= batch) return;

    const int start = starts[b];
    const int end   = starts[b + 1];

    float sd[16];
    #pragma unroll
    for (int d = 0; d < 16; ++d) sd[d] = 0.f;
    float ssq = 0.f;   // segsum of x_d^2 (partial over this lane's elements)
    float slin = 0.f;  // segsum of lw[id]

    for (int i = start + wl; i < end; i += 64) {
        const int id = ids[i];
        const float* row = cw + ((size_t)id << 4);
        const float4 x0 = *reinterpret_cast<const float4*>(row);
        const float4 x1 = *reinterpret_cast<const float4*>(row + 4);
        const float4 x2 = *reinterpret_cast<const float4*>(row + 8);
        const float4 x3 = *reinterpret_cast<const float4*>(row + 12);
        slin += lw[id];
        sd[ 0] += x0.x; sd[ 1] += x0.y; sd[ 2] += x0.z; sd[ 3] += x0.w;
        sd[ 4] += x1.x; sd[ 5] += x1.y; sd[ 6] += x1.z; sd[ 7] += x1.w;
        sd[ 8] += x2.x; sd[ 9] += x2.y; sd[10] += x2.z; sd[11] += x2.w;
        sd[12] += x3.x; sd[13] += x3.y; sd[14] += x3.z; sd[15] += x3.w;
        ssq = fmaf(x0.x, x0.x, ssq); ssq = fmaf(x0.y, x0.y, ssq);
        ssq = fmaf(x0.z, x0.z, ssq); ssq = fmaf(x0.w, x0.w, ssq);
        ssq = fmaf(x1.x, x1.x, ssq); ssq = fmaf(x1.y, x1.y, ssq);
        ssq = fmaf(x1.z, x1.z, ssq); ssq = fmaf(x1.w, x1.w, ssq);
        ssq = fmaf(x2.x, x2.x, ssq); ssq = fmaf(x2.y, x2.y, ssq);
        ssq = fmaf(x2.z, x2.z, ssq); ssq = fmaf(x2.w, x2.w, ssq);
        ssq = fmaf(x3.x, x3.x, ssq); ssq = fmaf(x3.y, x3.y, ssq);
        ssq = fmaf(x3.w, x3.w, ssq); ssq = fmaf(x3.z, x3.z, ssq);
    }

    // Butterfly-reduce all 18 accumulators across the 64 lanes.
    #pragma unroll
    for (int m = 1; m < 64; m <<= 1) {
        #pragma unroll
        for (int d = 0; d < 16; ++d) sd[d] += __shfl_xor(sd[d], m);
        ssq  += __shfl_xor(ssq,  m);
        slin += __shfl_xor(slin, m);
    }

    if (wl == 0) {
        float q = 0.f;
        #pragma unroll
        for (int d = 0; d < 16; ++d) q = fmaf(sd[d], sd[d], q);
        const float logit = bias[0] + slin + 0.5f * (q - ssq);
        const float adj   = logit;  // + log(NEG_SAMPLING_RATE=1) == 0
        out[b]             = logit;
        out[batch + b]     = adj;
        out[2 * batch + b] = 1.0f / (1.0f + expf(-adj));
    }
}

extern "C" void kernel_launch(void* const* d_in, const int* in_sizes, int n_in,
                              void* d_out, int out_size, void* d_ws, size_t ws_size,
                              hipStream_t stream) {
    const int*   ids  = (const int*)d_in[0];
    const int*   segs = (const int*)d_in[1];
    const float* bias = (const float*)d_in[3];
    const float* lw   = (const float*)d_in[4];
    const float* cw   = (const float*)d_in[5];
    float*       out  = (float*)d_out;

    const int nnz   = in_sizes[0];
    const int batch = out_size / 3;

    int* starts = (int*)d_ws;  // batch+1 ints, fully rewritten every launch

    seg_starts_kernel<<<(nnz + 255) / 256, 256, 0, stream>>>(segs, starts, nnz, batch);

    const int waves_per_block = 4;
    const int grid = (batch + waves_per_block - 1) / waves_per_block;
    fm_fused_kernel<<<grid, 256, 0, stream>>>(ids, starts, bias, lw, cw, out, batch);
}